// Round 9
// baseline (325.780 us; speedup 1.0000x reference)
//
#include <hip/hip_runtime.h>

typedef __bf16 bf16;
typedef __bf16 bf16x4 __attribute__((ext_vector_type(4)));
typedef __bf16 bf16x8 __attribute__((ext_vector_type(8)));
typedef float  f32x4  __attribute__((ext_vector_type(4)));

constexpr int Bb = 8, Ss = 1024, Dd = 1024, Hh = 16, HDd = 64;
constexpr int Mm = Bb * Ss;   // 8192
constexpr int Kk = 1024;

// ---------------- fused cast f32 -> bf16 (5 segments, float4 chunks) ----------------
struct CastArgs {
  const float* src[5];
  bf16* dst[5];
  int cum[5];
};
__global__ void cast_all(CastArgs a, int tot) {
  int i = blockIdx.x * blockDim.x + threadIdx.x;
  if (i >= tot) return;
  int s, base;
  if (i < a.cum[0])      { s = 0; base = 0; }
  else if (i < a.cum[1]) { s = 1; base = a.cum[0]; }
  else if (i < a.cum[2]) { s = 2; base = a.cum[1]; }
  else if (i < a.cum[3]) { s = 3; base = a.cum[2]; }
  else                   { s = 4; base = a.cum[3]; }
  int j = i - base;
  float4 v = reinterpret_cast<const float4*>(a.src[s])[j];
  bf16x4 o = { (bf16)v.x, (bf16)v.y, (bf16)v.z, (bf16)v.w };
  reinterpret_cast<bf16x4*>(a.dst[s])[j] = o;
}

// ---------------- shared NT GEMM core: 128x128 tile, BK=64, XOR-swizzled LDS ----------------
__device__ __forceinline__ void gemm_loop(const bf16* __restrict__ A, const bf16* __restrict__ Bm,
                                          int bm, int bn, unsigned char* As, unsigned char* Bs,
                                          int w, int lane, int l15, int g, f32x4 (&acc)[4][4]) {
  const bf16* srcA[4];
  const bf16* srcB[4];
#pragma unroll
  for (int i = 0; i < 4; ++i) {
    int gch = (w * 4 + i) * 64 + lane;  // chunk id 0..1023
    int r = gch >> 3, c = gch & 7, cs = c ^ (r & 7);
    srcA[i] = A  + (size_t)(bm * 128 + r) * Kk + cs * 8;
    srcB[i] = Bm + (size_t)(bn * 128 + r) * Kk + cs * 8;
  }
  for (int kt = 0; kt < Kk / 64; ++kt) {
    __syncthreads();
#pragma unroll
    for (int i = 0; i < 4; ++i) {
      __builtin_amdgcn_global_load_lds(
          (const __attribute__((address_space(1))) void*)(srcA[i] + kt * 64),
          (__attribute__((address_space(3))) void*)(As + (w * 4 + i) * 1024), 16, 0, 0);
      __builtin_amdgcn_global_load_lds(
          (const __attribute__((address_space(1))) void*)(srcB[i] + kt * 64),
          (__attribute__((address_space(3))) void*)(Bs + (w * 4 + i) * 1024), 16, 0, 0);
    }
    __syncthreads();
#pragma unroll
    for (int kk = 0; kk < 2; ++kk) {
      const int kb = kk * 64 + g * 16;
      bf16x8 af[4], bfr[4];
#pragma unroll
      for (int mi = 0; mi < 4; ++mi) {
        int row = ((w >> 1) * 64) + mi * 16 + l15;
        af[mi] = *reinterpret_cast<const bf16x8*>(As + row * 128 + (kb ^ ((row & 7) << 4)));
      }
#pragma unroll
      for (int ni = 0; ni < 4; ++ni) {
        int row = ((w & 1) * 64) + ni * 16 + l15;
        bfr[ni] = *reinterpret_cast<const bf16x8*>(Bs + row * 128 + (kb ^ ((row & 7) << 4)));
      }
#pragma unroll
      for (int mi = 0; mi < 4; ++mi)
#pragma unroll
        for (int ni = 0; ni < 4; ++ni)
          acc[mi][ni] = __builtin_amdgcn_mfma_f32_16x16x32_bf16(af[mi], bfr[ni], acc[mi][ni], 0, 0, 0);
    }
  }
}

// ---------------- fused QKV projection ----------------
// z=0: Q = (x@Wq^T + bq)*(0.125*log2e) -> [b,h,s,hd]  (exp(s) computed as exp2(s') downstream)
// z=1: K -> [b,h,s,hd]; z=2: V^T -> [b,h,hd,s]
__global__ __launch_bounds__(256) void gemm_qkv(const bf16* __restrict__ x,
                                                const bf16* __restrict__ wq, const bf16* __restrict__ wk,
                                                const bf16* __restrict__ wv,
                                                const float* __restrict__ bq, const float* __restrict__ bk,
                                                const float* __restrict__ bv,
                                                bf16* __restrict__ Qo, bf16* __restrict__ Ko,
                                                bf16* __restrict__ Vto) {
  const int tid = threadIdx.x;
  const int lane = tid & 63;
  const int w = tid >> 6;
  const int l15 = lane & 15, g = lane >> 4;
  const int z = blockIdx.z;

  const bf16* A; const bf16* Bm; int bm, bn;
  if (z < 2) { A = x; Bm = z ? wk : wq; bm = blockIdx.x; bn = blockIdx.y; }
  else       { A = wv; Bm = x;          bm = blockIdx.y; bn = blockIdx.x; }

  __shared__ __align__(16) unsigned char As[128 * 128];
  __shared__ __align__(16) unsigned char Bs[128 * 128];
  f32x4 acc[4][4] = {};
  gemm_loop(A, Bm, bm, bn, As, Bs, w, lane, l15, g, acc);

  const int wr = (w >> 1) * 64, wc = (w & 1) * 64;
  if (z < 2) {
    const float* bias = z ? bk : bq;
    bf16* out = z ? Ko : Qo;
    const float scale = z ? 1.f : 0.125f * 1.44269504088896340736f;
#pragma unroll
    for (int ni = 0; ni < 4; ++ni) {
      int col = bn * 128 + wc + ni * 16 + l15;
      float bv_ = bias[col];
#pragma unroll
      for (int mi = 0; mi < 4; ++mi)
#pragma unroll
        for (int r = 0; r < 4; ++r) {
          int row = bm * 128 + wr + mi * 16 + g * 4 + r;
          float val = (acc[mi][ni][r] + bv_) * scale;
          size_t adr = ((size_t)((row >> 10) * Hh + (col >> 6)) * Ss + (row & 1023)) * HDd + (col & 63);
          out[adr] = (bf16)val;
        }
    }
  } else {  // V^T: row = d-index, col = bs-index, bias per row
#pragma unroll
    for (int mi = 0; mi < 4; ++mi)
#pragma unroll
      for (int r = 0; r < 4; ++r) {
        int row = bm * 128 + wr + mi * 16 + g * 4 + r;
        float bv_ = bv[row];
#pragma unroll
        for (int ni = 0; ni < 4; ++ni) {
          int col = bn * 128 + wc + ni * 16 + l15;
          size_t adr = ((size_t)((col >> 10) * Hh + (row >> 6)) * HDd + (row & 63)) * Ss + (col & 1023);
          Vto[adr] = (bf16)(acc[mi][ni][r] + bv_);
        }
      }
  }
}

// ---------------- final projection: out = ctx @ Wf^T + bf (f32) ----------------
__global__ __launch_bounds__(256) void gemm_out(const bf16* __restrict__ A, const bf16* __restrict__ Bm,
                                                const float* __restrict__ bias, float* __restrict__ out) {
  const int tid = threadIdx.x;
  const int lane = tid & 63;
  const int w = tid >> 6;
  const int l15 = lane & 15, g = lane >> 4;
  const int bn = blockIdx.x, bm = blockIdx.y;
  __shared__ __align__(16) unsigned char As[128 * 128];
  __shared__ __align__(16) unsigned char Bs[128 * 128];
  f32x4 acc[4][4] = {};
  gemm_loop(A, Bm, bm, bn, As, Bs, w, lane, l15, g, acc);
  const int wr = (w >> 1) * 64, wc = (w & 1) * 64;
#pragma unroll
  for (int ni = 0; ni < 4; ++ni) {
    int col = bn * 128 + wc + ni * 16 + l15;
    float bv_ = bias[col];
#pragma unroll
    for (int mi = 0; mi < 4; ++mi)
#pragma unroll
      for (int r = 0; r < 4; ++r) {
        int row = bm * 128 + wr + mi * 16 + g * 4 + r;
        out[(size_t)row * Dd + col] = acc[mi][ni][r] + bv_;
      }
  }
}

// ---------------- fused attention ----------------
// R6 structure (1024 blocks, 512 thr = 8 waves, QBLK=128, KVBLK=128, 2 blocks/CU) with
// pass 1 rewritten BARRIER-FREE: K fragments are 16B/lane contiguous -> loaded straight
// from L2 into registers (no LDS, no staging, no barriers in pass 1). The compiler
// software-pipelines the load->MFMA->exp2 stream per wave; waves drift freely and rejoin
// at one barrier before pass 2. Pass-2 entry (K0/V0) is pre-staged at pass-1 top; in-order
// vmcnt retirement guarantees it is resident by the pass boundary.
// Pass 2 unchanged from R6 (verified): K dbuf slabs 0/1, V dbuf 2/3, counted vmcnt(8)
// keeps the 8 probs stores in flight across each phase barrier; plain (allocating) stores
// so L2 merges 64B half-line pairs (NT regressed 45us in R8).
// Q pre-scaled by 0.125*log2e -> exp(s) == exp2(s'), one v_exp per element, no mul.
#define WAITV(n) asm volatile("s_waitcnt vmcnt(" #n ")" ::: "memory")
#define PHASE_BAR { __builtin_amdgcn_s_barrier(); __builtin_amdgcn_sched_barrier(0); }

__global__ __launch_bounds__(512, 4) void attn_fused(const bf16* __restrict__ Q,
                                                     const bf16* __restrict__ Kt,
                                                     const bf16* __restrict__ Vt,
                                                     float* __restrict__ probs,
                                                     bf16* __restrict__ ctx) {
  const int tid = threadIdx.x;
  const int lane = tid & 63;
  const int w = tid >> 6;
  const int l15 = lane & 15, g = lane >> 4;
  const int bid = blockIdx.x;
  const int bh = (bid & 7) * 16 + ((bid >> 3) & 15);  // same head -> same bid%8 -> same XCD
  const int qt = bid >> 7;
  const int q0 = qt * 128 + w * 16;

  __shared__ __align__(16) unsigned char KV[4][16384];  // pass 2: K slabs 0/1, V slabs 2/3
  __shared__ __align__(16) bf16 Ps[8][16][40];          // per-wave P chunk (32 k + pad)

  // Q fragment (B-operand): lane holds Q[q0+l15][g*8..+7] and +32 (pre-scaled 0.125*log2e)
  bf16x8 qf0, qf1;
  {
    const bf16* qp = Q + ((size_t)bh * Ss + q0 + l15) * HDd + g * 8;
    qf0 = *reinterpret_cast<const bf16x8*>(qp);
    qf1 = *reinterpret_cast<const bf16x8*>(qp + 32);
  }
  const bf16* kbase = Kt + (size_t)bh * Ss * HDd;
  const bf16* vbase = Vt + (size_t)bh * HDd * Ss;

  // staging sources (source chunk pre-swizzled; global_load_lds dest = wave base + lane*16)
  const bf16* ksrc[2];
  const bf16* vsrc[2];
#pragma unroll
  for (int i = 0; i < 2; ++i) {
    int ch = i * 512 + tid;
    int kr = ch >> 3, kc = (ch & 7) ^ (kr & 7);
    ksrc[i] = kbase + (size_t)kr * HDd + kc * 8;
    int vr = ch >> 4, vc = (ch & 15) ^ (vr & 15);
    vsrc[i] = vbase + (size_t)vr * Ss + vc * 8;
  }

#define SK(slab, t)                                                                       \
  {                                                                                       \
    _Pragma("unroll") for (int i = 0; i < 2; ++i)                                         \
        __builtin_amdgcn_global_load_lds(                                                 \
            (const __attribute__((address_space(1))) void*)(ksrc[i] + (size_t)(t) * 128 * HDd), \
            (__attribute__((address_space(3))) void*)(KV[slab] + (i * 512 + w * 64) * 16),\
            16, 0, 0);                                                                    \
  }
#define SV(slab, t)                                                                       \
  {                                                                                       \
    _Pragma("unroll") for (int i = 0; i < 2; ++i)                                         \
        __builtin_amdgcn_global_load_lds(                                                 \
            (const __attribute__((address_space(1))) void*)(vsrc[i] + (t) * 128),         \
            (__attribute__((address_space(3))) void*)(KV[slab] + (i * 512 + w * 64) * 16),\
            16, 0, 0);                                                                    \
  }

  auto kread = [&](int slab, int nk, int half) -> bf16x8 {
    int row = nk * 16 + l15;                       // row & 7 == l15 & 7
    int chunk = (half * 4 + g) ^ (l15 & 7);
    return *reinterpret_cast<const bf16x8*>(KV[slab] + row * 128 + chunk * 16);
  };
  auto vread = [&](int slab, int nkp, int ni) -> bf16x8 {
    int row = ni * 16 + l15;                       // row & 15 == l15
    int chunk = (nkp * 4 + g) ^ l15;
    return *reinterpret_cast<const bf16x8*>(KV[slab] + row * 256 + chunk * 16);
  };

  // ---- pass 1 (barrier-free): row sum of exp2(score); K frags straight from L2 ----
  float lr0 = 0.f, lr1 = 0.f, lr2 = 0.f, lr3 = 0.f;
  SK(0, 0); SV(2, 0);   // pre-stage pass-2 entry; oldest in queue, retires during pass 1
  {
    const bf16* const kf = kbase + (size_t)l15 * HDd + g * 8;
    for (int kt = 0; kt < 8; ++kt) {
#pragma unroll
      for (int nk = 0; nk < 8; ++nk) {
        const bf16* kp = kf + (size_t)(kt * 128 + nk * 16) * HDd;
        bf16x8 k0 = *reinterpret_cast<const bf16x8*>(kp);
        bf16x8 k1 = *reinterpret_cast<const bf16x8*>(kp + 32);
        f32x4 sc = {0.f, 0.f, 0.f, 0.f};
        sc = __builtin_amdgcn_mfma_f32_16x16x32_bf16(k0, qf0, sc, 0, 0, 0);
        sc = __builtin_amdgcn_mfma_f32_16x16x32_bf16(k1, qf1, sc, 0, 0, 0);
        lr0 += __builtin_amdgcn_exp2f(sc[0]);
        lr1 += __builtin_amdgcn_exp2f(sc[1]);
        lr2 += __builtin_amdgcn_exp2f(sc[2]);
        lr3 += __builtin_amdgcn_exp2f(sc[3]);
      }
    }
  }
  float lsum = (lr0 + lr1) + (lr2 + lr3);
  lsum += __shfl_xor(lsum, 16, 64);
  lsum += __shfl_xor(lsum, 32, 64);
  const float rl = 1.f / lsum;

  // all pass-1 loads consumed -> per-wave vmem queue empty (K0/V0 were oldest, retired);
  // one barrier makes every wave's K0/V0 staging visible block-wide.
  __syncthreads();
  __builtin_amdgcn_sched_barrier(0);

  float* const prow = probs + ((size_t)bh * Ss + q0 + l15) * Ss;
  f32x4 cacc[4] = {};

  // ---- pass 2 (ascending; K[kt] slab kt&1, V[kt] slab 2+(kt&1); K0/V0 already resident) ----
  for (int kt = 0; kt < 8; ++kt) {
    if (kt < 7) { SK((kt + 1) & 1, kt + 1); SV(2 + ((kt + 1) & 1), kt + 1); }
    __builtin_amdgcn_sched_barrier(0);   // pin the 4 loads before compute (exact queue count)
    const int ks = kt & 1, vs = 2 + (kt & 1);
#pragma unroll
    for (int nkp = 0; nkp < 4; ++nkp) {
#pragma unroll
      for (int h = 0; h < 2; ++h) {
        int nk = nkp * 2 + h;
        f32x4 sc = {0.f, 0.f, 0.f, 0.f};
        bf16x8 k0 = kread(ks, nk, 0), k1 = kread(ks, nk, 1);
        __builtin_amdgcn_s_setprio(1);
        sc = __builtin_amdgcn_mfma_f32_16x16x32_bf16(k0, qf0, sc, 0, 0, 0);
        sc = __builtin_amdgcn_mfma_f32_16x16x32_bf16(k1, qf1, sc, 0, 0, 0);
        __builtin_amdgcn_s_setprio(0);
        f32x4 pv;
#pragma unroll
        for (int r = 0; r < 4; ++r) pv[r] = __builtin_amdgcn_exp2f(sc[r]) * rl;
        *reinterpret_cast<f32x4*>(prow + kt * 128 + nk * 16 + g * 4) = pv;  // plain store
        bf16x4 pb = { (bf16)pv[0], (bf16)pv[1], (bf16)pv[2], (bf16)pv[3] };
        *reinterpret_cast<bf16x4*>(&Ps[w][l15][h * 16 + g * 4]) = pb;  // one ds_write_b64
      }
      bf16x8 pf = *reinterpret_cast<const bf16x8*>(&Ps[w][l15][g * 8]);
      bf16x8 vf0 = vread(vs, nkp, 0), vf1 = vread(vs, nkp, 1);
      bf16x8 vf2 = vread(vs, nkp, 2), vf3 = vread(vs, nkp, 3);
      __builtin_amdgcn_s_setprio(1);
      cacc[0] = __builtin_amdgcn_mfma_f32_16x16x32_bf16(pf, vf0, cacc[0], 0, 0, 0);
      cacc[1] = __builtin_amdgcn_mfma_f32_16x16x32_bf16(pf, vf1, cacc[1], 0, 0, 0);
      cacc[2] = __builtin_amdgcn_mfma_f32_16x16x32_bf16(pf, vf2, cacc[2], 0, 0, 0);
      cacc[3] = __builtin_amdgcn_mfma_f32_16x16x32_bf16(pf, vf3, cacc[3], 0, 0, 0);
      __builtin_amdgcn_s_setprio(0);
    }
    if (kt < 7) {
      WAITV(8);   // retires the 4 next-tile loads; the 8 current probs stores stay in flight
      PHASE_BAR;
    }
  }
#undef SK
#undef SV

  // ctx: [b][s][h*64+hd] bf16 (PV D layout: row g*4+r = q offset, col l15 = hd)
  const int bb = bh >> 4, hh = bh & 15;
#pragma unroll
  for (int ni = 0; ni < 4; ++ni)
#pragma unroll
    for (int r = 0; r < 4; ++r) {
      int q = q0 + g * 4 + r;
      ctx[((size_t)bb * Ss + q) * Dd + hh * 64 + ni * 16 + l15] = (bf16)cacc[ni][r];
    }
}

// ---------------- launch ----------------
extern "C" void kernel_launch(void* const* d_in, const int* in_sizes, int n_in,
                              void* d_out, int out_size, void* d_ws, size_t ws_size,
                              hipStream_t stream) {
  (void)in_sizes; (void)n_in; (void)out_size; (void)ws_size;
  const float* x   = (const float*)d_in[0];
  const float* Wq  = (const float*)d_in[1];
  const float* bq  = (const float*)d_in[2];
  const float* Wk  = (const float*)d_in[3];
  const float* bk  = (const float*)d_in[4];
  const float* Wv  = (const float*)d_in[5];
  const float* bv  = (const float*)d_in[6];
  const float* Wf  = (const float*)d_in[7];
  const float* bfp = (const float*)d_in[8];

  char* ws = (char*)d_ws;
  size_t off = 0;
  auto alloc = [&](size_t n) { void* p = ws + off; off += (n + 255) & ~(size_t)255; return p; };
  bf16* xb   = (bf16*)alloc((size_t)Mm * Dd * 2);
  bf16* wqb  = (bf16*)alloc((size_t)Dd * Dd * 2);
  bf16* wkb  = (bf16*)alloc((size_t)Dd * Dd * 2);
  bf16* wvb  = (bf16*)alloc((size_t)Dd * Dd * 2);
  bf16* wfb  = (bf16*)alloc((size_t)Dd * Dd * 2);
  bf16* Qb   = (bf16*)alloc((size_t)Mm * Dd * 2);
  bf16* Kb   = (bf16*)alloc((size_t)Mm * Dd * 2);
  bf16* Vtb  = (bf16*)alloc((size_t)Mm * Dd * 2);
  bf16* ctxb = (bf16*)alloc((size_t)Mm * Dd * 2);

  CastArgs ca;
  ca.src[0] = x;  ca.dst[0] = xb;  int n0 = Mm * Dd / 4;
  ca.src[1] = Wq; ca.dst[1] = wqb; int nw = Dd * Dd / 4;
  ca.src[2] = Wk; ca.dst[2] = wkb;
  ca.src[3] = Wv; ca.dst[3] = wvb;
  ca.src[4] = Wf; ca.dst[4] = wfb;
  ca.cum[0] = n0; ca.cum[1] = n0 + nw; ca.cum[2] = n0 + 2 * nw;
  ca.cum[3] = n0 + 3 * nw; ca.cum[4] = n0 + 4 * nw;
  int tot = ca.cum[4];
  cast_all<<<(tot + 255) / 256, 256, 0, stream>>>(ca, tot);

  gemm_qkv<<<dim3(Mm / 128, Dd / 128, 3), 256, 0, stream>>>(xb, wqb, wkb, wvb, bq, bk, bv, Qb, Kb, Vtb);

  float* probs = (float*)d_out + (size_t)Mm * Dd;
  attn_fused<<<dim3(Bb * Hh * 8), 512, 0, stream>>>(Qb, Kb, Vtb, probs, ctxb);

  gemm_out<<<dim3(Dd / 128, Mm / 128), 256, 0, stream>>>(ctxb, wfb, bfp, (float*)d_out);
}

// Round 10
// 261.539 us; speedup vs baseline: 1.2456x; 1.2456x over previous
//
#include <hip/hip_runtime.h>

typedef __bf16 bf16;
typedef __bf16 bf16x4 __attribute__((ext_vector_type(4)));
typedef __bf16 bf16x8 __attribute__((ext_vector_type(8)));
typedef float  f32x4  __attribute__((ext_vector_type(4)));

constexpr int Bb = 8, Ss = 1024, Dd = 1024, Hh = 16, HDd = 64;
constexpr int Mm = Bb * Ss;   // 8192
constexpr int Kk = 1024;

// ---------------- fused cast f32 -> bf16 (5 segments, float4 chunks) ----------------
struct CastArgs {
  const float* src[5];
  bf16* dst[5];
  int cum[5];
};
__global__ void cast_all(CastArgs a, int tot) {
  int i = blockIdx.x * blockDim.x + threadIdx.x;
  if (i >= tot) return;
  int s, base;
  if (i < a.cum[0])      { s = 0; base = 0; }
  else if (i < a.cum[1]) { s = 1; base = a.cum[0]; }
  else if (i < a.cum[2]) { s = 2; base = a.cum[1]; }
  else if (i < a.cum[3]) { s = 3; base = a.cum[2]; }
  else                   { s = 4; base = a.cum[3]; }
  int j = i - base;
  float4 v = reinterpret_cast<const float4*>(a.src[s])[j];
  bf16x4 o = { (bf16)v.x, (bf16)v.y, (bf16)v.z, (bf16)v.w };
  reinterpret_cast<bf16x4*>(a.dst[s])[j] = o;
}

// ---------------- shared NT GEMM core: 128x128 tile, BK=64, XOR-swizzled LDS ----------------
__device__ __forceinline__ void gemm_loop(const bf16* __restrict__ A, const bf16* __restrict__ Bm,
                                          int bm, int bn, unsigned char* As, unsigned char* Bs,
                                          int w, int lane, int l15, int g, f32x4 (&acc)[4][4]) {
  const bf16* srcA[4];
  const bf16* srcB[4];
#pragma unroll
  for (int i = 0; i < 4; ++i) {
    int gch = (w * 4 + i) * 64 + lane;  // chunk id 0..1023
    int r = gch >> 3, c = gch & 7, cs = c ^ (r & 7);
    srcA[i] = A  + (size_t)(bm * 128 + r) * Kk + cs * 8;
    srcB[i] = Bm + (size_t)(bn * 128 + r) * Kk + cs * 8;
  }
  for (int kt = 0; kt < Kk / 64; ++kt) {
    __syncthreads();
#pragma unroll
    for (int i = 0; i < 4; ++i) {
      __builtin_amdgcn_global_load_lds(
          (const __attribute__((address_space(1))) void*)(srcA[i] + kt * 64),
          (__attribute__((address_space(3))) void*)(As + (w * 4 + i) * 1024), 16, 0, 0);
      __builtin_amdgcn_global_load_lds(
          (const __attribute__((address_space(1))) void*)(srcB[i] + kt * 64),
          (__attribute__((address_space(3))) void*)(Bs + (w * 4 + i) * 1024), 16, 0, 0);
    }
    __syncthreads();
#pragma unroll
    for (int kk = 0; kk < 2; ++kk) {
      const int kb = kk * 64 + g * 16;
      bf16x8 af[4], bfr[4];
#pragma unroll
      for (int mi = 0; mi < 4; ++mi) {
        int row = ((w >> 1) * 64) + mi * 16 + l15;
        af[mi] = *reinterpret_cast<const bf16x8*>(As + row * 128 + (kb ^ ((row & 7) << 4)));
      }
#pragma unroll
      for (int ni = 0; ni < 4; ++ni) {
        int row = ((w & 1) * 64) + ni * 16 + l15;
        bfr[ni] = *reinterpret_cast<const bf16x8*>(Bs + row * 128 + (kb ^ ((row & 7) << 4)));
      }
#pragma unroll
      for (int mi = 0; mi < 4; ++mi)
#pragma unroll
        for (int ni = 0; ni < 4; ++ni)
          acc[mi][ni] = __builtin_amdgcn_mfma_f32_16x16x32_bf16(af[mi], bfr[ni], acc[mi][ni], 0, 0, 0);
    }
  }
}

// ---------------- fused QKV projection (1D grid, XCD-clustered) ----------------
// All 24 (bn,z) blocks sharing one bm's A-panel (256 KB of x) run consecutively on ONE XCD
// -> A-panel stays L2-resident. Decode: id = xcd + 8*(bmg*24 + (z*8+bn)), bm = xcd*8+bmg.
// z=0: Q = (x@Wq^T + bq)*(0.125*log2e) -> [b,h,s,hd]; z=1: K; z=2: V^T -> [b,h,hd,s]
__global__ __launch_bounds__(256) void gemm_qkv(const bf16* __restrict__ x,
                                                const bf16* __restrict__ wq, const bf16* __restrict__ wk,
                                                const bf16* __restrict__ wv,
                                                const float* __restrict__ bq, const float* __restrict__ bk,
                                                const float* __restrict__ bv,
                                                bf16* __restrict__ Qo, bf16* __restrict__ Ko,
                                                bf16* __restrict__ Vto) {
  const int tid = threadIdx.x;
  const int lane = tid & 63;
  const int w = tid >> 6;
  const int l15 = lane & 15, g = lane >> 4;

  const int id = blockIdx.x;
  const int xcd = id & 7, slot = id >> 3;       // 192 slots per XCD
  const int bmg = slot / 24, rem = slot % 24;   // 8 bm-groups x 24 (bn,z)
  const int bmx = xcd * 8 + bmg;                // A-panel index (0..63 over M=8192)
  const int bnx = rem & 7;                      // 0..7 over N=1024
  const int z = rem >> 3;                       // 0..2

  const bf16* A; const bf16* Bm; int bm, bn;
  if (z < 2) { A = x; Bm = z ? wk : wq; bm = bmx; bn = bnx; }
  else       { A = wv; Bm = x;          bm = bnx; bn = bmx; }  // V^T: M=Dd (wv rows), N=Mm (x rows)

  __shared__ __align__(16) unsigned char As[128 * 128];
  __shared__ __align__(16) unsigned char Bs[128 * 128];
  f32x4 acc[4][4] = {};
  gemm_loop(A, Bm, bm, bn, As, Bs, w, lane, l15, g, acc);

  const int wr = (w >> 1) * 64, wc = (w & 1) * 64;
  if (z < 2) {
    const float* bias = z ? bk : bq;
    bf16* out = z ? Ko : Qo;
    const float scale = z ? 1.f : 0.125f * 1.44269504088896340736f;
#pragma unroll
    for (int ni = 0; ni < 4; ++ni) {
      int col = bn * 128 + wc + ni * 16 + l15;
      float bv_ = bias[col];
#pragma unroll
      for (int mi = 0; mi < 4; ++mi)
#pragma unroll
        for (int r = 0; r < 4; ++r) {
          int row = bm * 128 + wr + mi * 16 + g * 4 + r;
          float val = (acc[mi][ni][r] + bv_) * scale;
          size_t adr = ((size_t)((row >> 10) * Hh + (col >> 6)) * Ss + (row & 1023)) * HDd + (col & 63);
          out[adr] = (bf16)val;
        }
    }
  } else {  // V^T: row = d-index, col = bs-index, bias per row
#pragma unroll
    for (int mi = 0; mi < 4; ++mi)
#pragma unroll
      for (int r = 0; r < 4; ++r) {
        int row = bm * 128 + wr + mi * 16 + g * 4 + r;
        float bv_ = bv[row];
#pragma unroll
        for (int ni = 0; ni < 4; ++ni) {
          int col = bn * 128 + wc + ni * 16 + l15;
          size_t adr = ((size_t)((col >> 10) * Hh + (row >> 6)) * HDd + (row & 63)) * Ss + (col & 1023);
          Vto[adr] = (bf16)(acc[mi][ni][r] + bv_);
        }
      }
  }
}

// ---------------- final projection (1D grid, XCD-clustered): out = ctx @ Wf^T + bf ----------------
__global__ __launch_bounds__(256) void gemm_out(const bf16* __restrict__ A, const bf16* __restrict__ Bm,
                                                const float* __restrict__ bias, float* __restrict__ out) {
  const int tid = threadIdx.x;
  const int lane = tid & 63;
  const int w = tid >> 6;
  const int l15 = lane & 15, g = lane >> 4;
  const int id = blockIdx.x;                    // 512 blocks
  const int xcd = id & 7, slot = id >> 3;       // 64 slots per XCD
  const int bm = xcd * 8 + (slot >> 3);         // 8 bn-blocks of one ctx-panel per XCD
  const int bn = slot & 7;
  __shared__ __align__(16) unsigned char As[128 * 128];
  __shared__ __align__(16) unsigned char Bs[128 * 128];
  f32x4 acc[4][4] = {};
  gemm_loop(A, Bm, bm, bn, As, Bs, w, lane, l15, g, acc);
  const int wr = (w >> 1) * 64, wc = (w & 1) * 64;
#pragma unroll
  for (int ni = 0; ni < 4; ++ni) {
    int col = bn * 128 + wc + ni * 16 + l15;
    float bv_ = bias[col];
#pragma unroll
    for (int mi = 0; mi < 4; ++mi)
#pragma unroll
      for (int r = 0; r < 4; ++r) {
        int row = bm * 128 + wr + mi * 16 + g * 4 + r;
        out[(size_t)row * Dd + col] = acc[mi][ni][r] + bv_;
      }
  }
}

// ---------------- fused attention (exact R6 structure + exp2) ----------------
// 1024 blocks, 512 thr = 8 waves, QBLK=128, KVBLK=128, 2 blocks/CU.
// Pass 1: K rotates through 4 slabs (prefetch depth 3); counted vmcnt(4/2/0).
// Pass 2: K dbuf slabs 0/1, V dbuf 2/3; phase-end vmcnt(8) keeps the 8 probs stores in
// flight, retires the 4 next-tile loads. Plain (allocating) probs stores (NT regressed, R8).
// Q pre-scaled by 0.125*log2e -> exp(s) == exp2(s') (validated R9, absmax unchanged).
#define WAITV(n) asm volatile("s_waitcnt vmcnt(" #n ")" ::: "memory")
#define PHASE_BAR { __builtin_amdgcn_s_barrier(); __builtin_amdgcn_sched_barrier(0); }

__global__ __launch_bounds__(512, 4) void attn_fused(const bf16* __restrict__ Q,
                                                     const bf16* __restrict__ Kt,
                                                     const bf16* __restrict__ Vt,
                                                     float* __restrict__ probs,
                                                     bf16* __restrict__ ctx) {
  const int tid = threadIdx.x;
  const int lane = tid & 63;
  const int w = tid >> 6;
  const int l15 = lane & 15, g = lane >> 4;
  const int bid = blockIdx.x;
  const int bh = (bid & 7) * 16 + ((bid >> 3) & 15);  // same head -> same bid%8 -> same XCD
  const int qt = bid >> 7;
  const int q0 = qt * 128 + w * 16;

  __shared__ __align__(16) unsigned char KV[4][16384];  // p1: K rotation; p2: K slabs 0/1, V 2/3
  __shared__ __align__(16) bf16 Ps[8][16][40];          // per-wave P chunk (32 k + pad)

  // Q fragment (B-operand): lane holds Q[q0+l15][g*8..+7] and +32 (pre-scaled 0.125*log2e)
  bf16x8 qf0, qf1;
  {
    const bf16* qp = Q + ((size_t)bh * Ss + q0 + l15) * HDd + g * 8;
    qf0 = *reinterpret_cast<const bf16x8*>(qp);
    qf1 = *reinterpret_cast<const bf16x8*>(qp + 32);
  }
  const bf16* kbase = Kt + (size_t)bh * Ss * HDd;
  const bf16* vbase = Vt + (size_t)bh * HDd * Ss;

  // staging sources (source chunk pre-swizzled; global_load_lds dest = wave base + lane*16)
  const bf16* ksrc[2];
  const bf16* vsrc[2];
#pragma unroll
  for (int i = 0; i < 2; ++i) {
    int ch = i * 512 + tid;
    int kr = ch >> 3, kc = (ch & 7) ^ (kr & 7);
    ksrc[i] = kbase + (size_t)kr * HDd + kc * 8;
    int vr = ch >> 4, vc = (ch & 15) ^ (vr & 15);
    vsrc[i] = vbase + (size_t)vr * Ss + vc * 8;
  }

#define SK(slab, t)                                                                       \
  {                                                                                       \
    _Pragma("unroll") for (int i = 0; i < 2; ++i)                                         \
        __builtin_amdgcn_global_load_lds(                                                 \
            (const __attribute__((address_space(1))) void*)(ksrc[i] + (size_t)(t) * 128 * HDd), \
            (__attribute__((address_space(3))) void*)(KV[slab] + (i * 512 + w * 64) * 16),\
            16, 0, 0);                                                                    \
  }
#define SV(slab, t)                                                                       \
  {                                                                                       \
    _Pragma("unroll") for (int i = 0; i < 2; ++i)                                         \
        __builtin_amdgcn_global_load_lds(                                                 \
            (const __attribute__((address_space(1))) void*)(vsrc[i] + (t) * 128),         \
            (__attribute__((address_space(3))) void*)(KV[slab] + (i * 512 + w * 64) * 16),\
            16, 0, 0);                                                                    \
  }

  auto kread = [&](int slab, int nk, int half) -> bf16x8 {
    int row = nk * 16 + l15;                       // row & 7 == l15 & 7
    int chunk = (half * 4 + g) ^ (l15 & 7);
    return *reinterpret_cast<const bf16x8*>(KV[slab] + row * 128 + chunk * 16);
  };
  auto vread = [&](int slab, int nkp, int ni) -> bf16x8 {
    int row = ni * 16 + l15;                       // row & 15 == l15
    int chunk = (nkp * 4 + g) ^ l15;
    return *reinterpret_cast<const bf16x8*>(KV[slab] + row * 256 + chunk * 16);
  };

  // ---- pass 1: row sum of exp2(score); lane's q = l15, k = g*4+r within nk*16 ----
  float lr0 = 0.f, lr1 = 0.f, lr2 = 0.f, lr3 = 0.f;
  SK(0, 0); SK(1, 1); SK(2, 2);     // prefetch depth 3
  __builtin_amdgcn_sched_barrier(0);
  WAITV(4);                          // K0 retired (K1,K2 in flight)
  PHASE_BAR;
  for (int kt = 0; kt < 8; ++kt) {
    if (kt <= 4)      { SK((kt + 3) & 3, kt + 3); }
    else if (kt == 7) { SK(0, 0); SV(2, 0); }     // pre-stage pass-2 entry
    __builtin_amdgcn_sched_barrier(0);
    const int ks = kt & 3;
#pragma unroll
    for (int nk = 0; nk < 8; ++nk) {
      f32x4 sc = {0.f, 0.f, 0.f, 0.f};
      bf16x8 k0 = kread(ks, nk, 0), k1 = kread(ks, nk, 1);
      __builtin_amdgcn_s_setprio(1);
      sc = __builtin_amdgcn_mfma_f32_16x16x32_bf16(k0, qf0, sc, 0, 0, 0);
      sc = __builtin_amdgcn_mfma_f32_16x16x32_bf16(k1, qf1, sc, 0, 0, 0);
      __builtin_amdgcn_s_setprio(0);
      lr0 += __builtin_amdgcn_exp2f(sc[0]);
      lr1 += __builtin_amdgcn_exp2f(sc[1]);
      lr2 += __builtin_amdgcn_exp2f(sc[2]);
      lr3 += __builtin_amdgcn_exp2f(sc[3]);
    }
    // per-wave queue: tiles outstanding after this phase's needs
    if (kt <= 4)      { WAITV(4); }  // next tile retired; 2 tiles (4 loads) in flight
    else if (kt == 5) { WAITV(2); }
    else              { WAITV(0); }  // kt=6: K7; kt=7: K0+V0 for pass 2
    PHASE_BAR;
  }
  float lsum = (lr0 + lr1) + (lr2 + lr3);
  lsum += __shfl_xor(lsum, 16, 64);
  lsum += __shfl_xor(lsum, 32, 64);
  const float rl = 1.f / lsum;

  float* const prow = probs + ((size_t)bh * Ss + q0 + l15) * Ss;
  f32x4 cacc[4] = {};

  // ---- pass 2 (ascending; K[kt] slab kt&1, V[kt] slab 2+(kt&1); K0/V0 staged above) ----
  for (int kt = 0; kt < 8; ++kt) {
    if (kt < 7) { SK((kt + 1) & 1, kt + 1); SV(2 + ((kt + 1) & 1), kt + 1); }
    __builtin_amdgcn_sched_barrier(0);   // pin the 4 loads before compute (exact queue count)
    const int ks = kt & 1, vs = 2 + (kt & 1);
#pragma unroll
    for (int nkp = 0; nkp < 4; ++nkp) {
#pragma unroll
      for (int h = 0; h < 2; ++h) {
        int nk = nkp * 2 + h;
        f32x4 sc = {0.f, 0.f, 0.f, 0.f};
        bf16x8 k0 = kread(ks, nk, 0), k1 = kread(ks, nk, 1);
        __builtin_amdgcn_s_setprio(1);
        sc = __builtin_amdgcn_mfma_f32_16x16x32_bf16(k0, qf0, sc, 0, 0, 0);
        sc = __builtin_amdgcn_mfma_f32_16x16x32_bf16(k1, qf1, sc, 0, 0, 0);
        __builtin_amdgcn_s_setprio(0);
        f32x4 pv;
#pragma unroll
        for (int r = 0; r < 4; ++r) pv[r] = __builtin_amdgcn_exp2f(sc[r]) * rl;
        *reinterpret_cast<f32x4*>(prow + kt * 128 + nk * 16 + g * 4) = pv;  // plain store
        bf16x4 pb = { (bf16)pv[0], (bf16)pv[1], (bf16)pv[2], (bf16)pv[3] };
        *reinterpret_cast<bf16x4*>(&Ps[w][l15][h * 16 + g * 4]) = pb;       // one ds_write_b64
      }
      bf16x8 pf = *reinterpret_cast<const bf16x8*>(&Ps[w][l15][g * 8]);
      bf16x8 vf0 = vread(vs, nkp, 0), vf1 = vread(vs, nkp, 1);
      bf16x8 vf2 = vread(vs, nkp, 2), vf3 = vread(vs, nkp, 3);
      __builtin_amdgcn_s_setprio(1);
      cacc[0] = __builtin_amdgcn_mfma_f32_16x16x32_bf16(pf, vf0, cacc[0], 0, 0, 0);
      cacc[1] = __builtin_amdgcn_mfma_f32_16x16x32_bf16(pf, vf1, cacc[1], 0, 0, 0);
      cacc[2] = __builtin_amdgcn_mfma_f32_16x16x32_bf16(pf, vf2, cacc[2], 0, 0, 0);
      cacc[3] = __builtin_amdgcn_mfma_f32_16x16x32_bf16(pf, vf3, cacc[3], 0, 0, 0);
      __builtin_amdgcn_s_setprio(0);
    }
    if (kt < 7) {
      WAITV(8);   // retires the 4 next-tile loads; the 8 current probs stores stay in flight
      PHASE_BAR;
    }
  }
#undef SK
#undef SV

  // ctx: [b][s][h*64+hd] bf16 (PV D layout: row g*4+r = q offset, col l15 = hd)
  const int bb = bh >> 4, hh = bh & 15;
#pragma unroll
  for (int ni = 0; ni < 4; ++ni)
#pragma unroll
    for (int r = 0; r < 4; ++r) {
      int q = q0 + g * 4 + r;
      ctx[((size_t)bb * Ss + q) * Dd + hh * 64 + ni * 16 + l15] = (bf16)cacc[ni][r];
    }
}

// ---------------- launch ----------------
extern "C" void kernel_launch(void* const* d_in, const int* in_sizes, int n_in,
                              void* d_out, int out_size, void* d_ws, size_t ws_size,
                              hipStream_t stream) {
  (void)in_sizes; (void)n_in; (void)out_size; (void)ws_size;
  const float* x   = (const float*)d_in[0];
  const float* Wq  = (const float*)d_in[1];
  const float* bq  = (const float*)d_in[2];
  const float* Wk  = (const float*)d_in[3];
  const float* bk  = (const float*)d_in[4];
  const float* Wv  = (const float*)d_in[5];
  const float* bv  = (const float*)d_in[6];
  const float* Wf  = (const float*)d_in[7];
  const float* bfp = (const float*)d_in[8];

  char* ws = (char*)d_ws;
  size_t off = 0;
  auto alloc = [&](size_t n) { void* p = ws + off; off += (n + 255) & ~(size_t)255; return p; };
  bf16* xb   = (bf16*)alloc((size_t)Mm * Dd * 2);
  bf16* wqb  = (bf16*)alloc((size_t)Dd * Dd * 2);
  bf16* wkb  = (bf16*)alloc((size_t)Dd * Dd * 2);
  bf16* wvb  = (bf16*)alloc((size_t)Dd * Dd * 2);
  bf16* wfb  = (bf16*)alloc((size_t)Dd * Dd * 2);
  bf16* Qb   = (bf16*)alloc((size_t)Mm * Dd * 2);
  bf16* Kb   = (bf16*)alloc((size_t)Mm * Dd * 2);
  bf16* Vtb  = (bf16*)alloc((size_t)Mm * Dd * 2);
  bf16* ctxb = (bf16*)alloc((size_t)Mm * Dd * 2);

  CastArgs ca;
  ca.src[0] = x;  ca.dst[0] = xb;  int n0 = Mm * Dd / 4;
  ca.src[1] = Wq; ca.dst[1] = wqb; int nw = Dd * Dd / 4;
  ca.src[2] = Wk; ca.dst[2] = wkb;
  ca.src[3] = Wv; ca.dst[3] = wvb;
  ca.src[4] = Wf; ca.dst[4] = wfb;
  ca.cum[0] = n0; ca.cum[1] = n0 + nw; ca.cum[2] = n0 + 2 * nw;
  ca.cum[3] = n0 + 3 * nw; ca.cum[4] = n0 + 4 * nw;
  int tot = ca.cum[4];
  cast_all<<<(tot + 255) / 256, 256, 0, stream>>>(ca, tot);

  gemm_qkv<<<dim3(64 * 8 * 3), 256, 0, stream>>>(xb, wqb, wkb, wvb, bq, bk, bv, Qb, Kb, Vtb);

  float* probs = (float*)d_out + (size_t)Mm * Dd;
  attn_fused<<<dim3(Bb * Hh * 8), 512, 0, stream>>>(Qb, Kb, Vtb, probs, ctxb);

  gemm_out<<<dim3(64 * 8), 256, 0, stream>>>(ctxb, wfb, bfp, (float*)d_out);
}